// Round 11
// baseline (333.130 us; speedup 1.0000x reference)
//
#include <hip/hip_runtime.h>
#include <hip/hip_bf16.h>

typedef __hip_bfloat16 bf16;
typedef unsigned short ushort_t;
typedef __attribute__((ext_vector_type(8))) short short8v;
typedef __attribute__((ext_vector_type(4))) float floatx4;

#define NEG_SLOPE 0.15f

__device__ __forceinline__ float us2f(unsigned short u) {
    unsigned int x = ((unsigned int)u) << 16;
    float f;
    __builtin_memcpy(&f, &x, 4);
    return f;
}
__device__ __forceinline__ unsigned short f2us(float v) {
    bf16 h = __float2bfloat16(v);
    unsigned short u;
    __builtin_memcpy(&u, &h, 2);
    return u;
}

// ---------------------------------------------------------- per-block dtype flag
// flag=1 if x is packed bf16, 0 if fp32. Votes on first 256 words of x.
// Requires blockDim.x >= 256; call before any early return.
__device__ __forceinline__ int block_flag(const unsigned int* __restrict__ xw) {
    __shared__ int cnt;
    if (threadIdx.x == 0) cnt = 0;
    __syncthreads();
    if (threadIdx.x < 256) {
        unsigned int w = xw[threadIdx.x];
        unsigned int e = (w >> 7) & 0xFF;
        if ((w & 0xFFFF) == 0 || (e >= 100 && e <= 140)) atomicAdd(&cnt, 1);
    }
    __syncthreads();
    return cnt >= 150;
}

// ---------------------------------------------------------------- prep kernel
// task types: K==0 -> fp32 convert; K>0 -> transpose W[K x Nn] -> bf16 Wt[Nn x K];
// K==-1 -> zero ints; K==-2 -> convert x to bf16 (grid-stride).
struct PrepDesc {
    const void* src[14];
    void* dst[14];
    int n[14];
    int K[14], Nn[14];
};

__global__ void prep_small_kernel(PrepDesc d, const void* __restrict__ xsrc) {
    int f = block_flag((const unsigned int*)xsrc);
    int t = blockIdx.y;
    int Kt = d.K[t];
    int nt = d.n[t];
    if (Kt == -2) {
        ushort_t* out = (ushort_t*)d.dst[t];
        const void* in = d.src[t];
        int stride = gridDim.x * blockDim.x;
        for (int i = blockIdx.x * blockDim.x + threadIdx.x; i < nt; i += stride)
            out[i] = f ? ((const unsigned short*)in)[i] : f2us(((const float*)in)[i]);
        return;
    }
    int i = blockIdx.x * blockDim.x + threadIdx.x;
    if (i >= nt) return;
    if (Kt == -1) {
        ((int*)d.dst[t])[i] = 0;
    } else if (Kt == 0) {
        ((float*)d.dst[t])[i] = f ? us2f(((const unsigned short*)d.src[t])[i])
                                  : ((const float*)d.src[t])[i];
    } else {
        int K = Kt, Nn = d.Nn[t];
        int n = i / K, k = i - n * K;
        size_t si = (size_t)k * Nn + n;
        ((ushort_t*)d.dst[t])[i] = f ? ((const unsigned short*)d.src[t])[si]
                                     : f2us(((const float*)d.src[t])[si]);
    }
}

// ---------------------------------------------------------------- CSR mega kernel
// One kernel: count_deg -> scan -> fill, nb=20 blocks x 1024 threads, software
// grid barriers (monotone counter; 20 blocks trivially co-resident on 256 CUs).
__device__ __forceinline__ void gbar(int* bar, int target) {
    __syncthreads();
    if (threadIdx.x == 0) {
        __hip_atomic_fetch_add(bar, 1, __ATOMIC_ACQ_REL, __HIP_MEMORY_SCOPE_AGENT);
        while (__hip_atomic_load(bar, __ATOMIC_ACQUIRE, __HIP_MEMORY_SCOPE_AGENT)
               < target) {}
    }
    __syncthreads();
}

__global__ __launch_bounds__(1024) void csr_mega_kernel(
    const int* __restrict__ src, const int* __restrict__ dst,
    int* __restrict__ deg, int* __restrict__ bar,
    int* __restrict__ offsets, int* __restrict__ cursor, float* __restrict__ dis,
    int* __restrict__ bsum, int2* __restrict__ edges,
    int E, int N, int Etot, int nb) {
    __shared__ int sh[1024];
    __shared__ int base_s;
    int tid = threadIdx.x;
    int b = blockIdx.x;
    int gtid = b * 1024 + tid;
    int gsz = nb * 1024;

    // phase 0: degree count
    for (int i = gtid; i < E; i += gsz) {
        int d = dst[i];
        d = d < 0 ? 0 : (d >= N ? N - 1 : d);
        atomicAdd(&deg[d], 1);
    }
    gbar(bar, nb);

    // phase 1: per-block inclusive scan of (deg+1)
    int v = (gtid < N) ? (deg[gtid] + 1) : 0;
    sh[tid] = v;
    __syncthreads();
    for (int off = 1; off < 1024; off <<= 1) {
        int t = (tid >= off) ? sh[tid - off] : 0;
        __syncthreads();
        sh[tid] += t;
        __syncthreads();
    }
    int inc = sh[tid];
    if (tid == 1023) bsum[b] = sh[1023];
    gbar(bar, 2 * nb);

    if (tid == 0) {
        int a = 0;
        for (int pb = 0; pb < b; ++pb) a += bsum[pb];
        base_s = a;
    }
    __syncthreads();
    if (gtid < N) {
        int base = base_s;
        int excl = base + inc - v;
        offsets[gtid] = excl;
        cursor[gtid] = excl;
        dis[gtid] = rsqrtf((float)v);
        if (gtid == N - 1) offsets[N] = base + inc;
    }
    gbar(bar, 3 * nb);

    // phase 2: fill edges[pos] = {src, bits(dis[src])}
    for (int i = gtid; i < Etot; i += gsz) {
        int s, d;
        if (i < E) { s = src[i]; d = dst[i]; }
        else { s = d = i - E; }
        s = s < 0 ? 0 : (s >= N ? N - 1 : s);
        d = d < 0 ? 0 : (d >= N ? N - 1 : d);
        int pos = atomicAdd(&cursor[d], 1);
        if (pos >= 0 && pos < Etot) edges[pos] = make_int2(s, __float_as_int(dis[s]));
    }
}

// ---------------------------------------------------------------- aggregation
template <int VEC> struct LdT;
template <> struct LdT<2> { typedef unsigned int T; };
template <> struct LdT<4> { typedef uint2 T; };

template <int VEC>
__device__ __forceinline__ void addv(typename LdT<VEC>::T u, float w, float* acc);
template <>
__device__ __forceinline__ void addv<2>(unsigned int u, float w, float* acc) {
    acc[0] += w * us2f((unsigned short)(u & 0xFFFF));
    acc[1] += w * us2f((unsigned short)(u >> 16));
}
template <>
__device__ __forceinline__ void addv<4>(uint2 u, float w, float* acc) {
    acc[0] += w * us2f((unsigned short)(u.x & 0xFFFF));
    acc[1] += w * us2f((unsigned short)(u.x >> 16));
    acc[2] += w * us2f((unsigned short)(u.y & 0xFFFF));
    acc[3] += w * us2f((unsigned short)(u.y >> 16));
}

// core gather+accumulate for one node; returns post-bias, post-lrelu values in outv
template <int VEC>
__device__ __forceinline__ void agg_core(
    const ushort_t* __restrict__ Hin, const int* __restrict__ offsets,
    const int2* __restrict__ edges, const float* __restrict__ dis,
    int node, int lane, int N, int Etot,
    const float* __restrict__ bias, int do_lrelu, float* outv) {
    typedef typename LdT<VEC>::T LT;
    const int F = VEC * 64;
    int beg = offsets[node], end = offsets[node + 1];
    beg = beg < 0 ? 0 : (beg > Etot ? Etot : beg);
    end = end < beg ? beg : (end > Etot ? Etot : end);

    float acc[VEC];
#pragma unroll
    for (int v = 0; v < VEC; ++v) acc[v] = 0.f;

    int fo = lane * VEC;
    int e = beg;
    for (; e + 8 <= end; e += 8) {
        int2 r[8];
#pragma unroll
        for (int j = 0; j < 8; ++j) r[j] = edges[e + j];
        LT u[8];
#pragma unroll
        for (int j = 0; j < 8; ++j) {
            int s = r[j].x;
            s = s < 0 ? 0 : (s >= N ? N - 1 : s);
            u[j] = *(const LT*)(Hin + (size_t)s * F + fo);
        }
#pragma unroll
        for (int j = 0; j < 8; ++j) addv<VEC>(u[j], __int_as_float(r[j].y), acc);
    }
    if (e + 4 <= end) {
        int2 r[4];
#pragma unroll
        for (int j = 0; j < 4; ++j) r[j] = edges[e + j];
        LT u[4];
#pragma unroll
        for (int j = 0; j < 4; ++j) {
            int s = r[j].x;
            s = s < 0 ? 0 : (s >= N ? N - 1 : s);
            u[j] = *(const LT*)(Hin + (size_t)s * F + fo);
        }
#pragma unroll
        for (int j = 0; j < 4; ++j) addv<VEC>(u[j], __int_as_float(r[j].y), acc);
        e += 4;
    }
    for (; e < end; ++e) {
        int2 r = edges[e];
        int s = r.x;
        s = s < 0 ? 0 : (s >= N ? N - 1 : s);
        LT u = *(const LT*)(Hin + (size_t)s * F + fo);
        addv<VEC>(u, __int_as_float(r.y), acc);
    }

    float dn = dis[node];
#pragma unroll
    for (int v = 0; v < VEC; ++v) {
        float a = acc[v] * dn;
        if (bias) a += bias[fo + v];
        if (do_lrelu) a = (a > 0.f) ? a : a * NEG_SLOPE;
        outv[v] = a;
    }
}

// standalone agg: bf16 packed output
template <int VEC>
__global__ __launch_bounds__(256) void agg_kernel(
    const ushort_t* __restrict__ Hin, ushort_t* __restrict__ OutB,
    const int* __restrict__ offsets, const int2* __restrict__ edges,
    const float* __restrict__ dis, int N, int Etot,
    const float* __restrict__ bias, int do_lrelu) {
    int lane = threadIdx.x & 63;
    int node = blockIdx.x * 4 + (threadIdx.x >> 6);
    if (node >= N) return;
    float outv[VEC];
    agg_core<VEC>(Hin, offsets, edges, dis, node, lane, N, Etot, bias, do_lrelu, outv);
    size_t base = (size_t)node * (VEC * 64) + lane * VEC;
    if (VEC == 2) {
        unsigned int w = ((unsigned int)f2us(outv[1]) << 16) | f2us(outv[0]);
        *(unsigned int*)(OutB + base) = w;
    } else {
        uint2 w;
        w.x = ((unsigned int)f2us(outv[1]) << 16) | f2us(outv[0]);
        w.y = ((unsigned int)f2us(outv[3]) << 16) | f2us(outv[2]);
        *(uint2*)(OutB + base) = w;
    }
}

// fused agg (VEC=2, F=128) + head MLP: H3 stays in fp32 registers, then
// 128->16 via wave butterfly, 16->32->2 lane-parallel, lane 0 stores.
__global__ __launch_bounds__(256) void agg_head_kernel(
    const ushort_t* __restrict__ Hin,
    const int* __restrict__ offsets, const int2* __restrict__ edges,
    const float* __restrict__ dis, int N, int Etot,
    const float* __restrict__ b3,
    const float* __restrict__ Wp, const float* __restrict__ bp,
    const float* __restrict__ Wf1, const float* __restrict__ bf1v,
    const float* __restrict__ Wf2, const float* __restrict__ bf2v,
    void* __restrict__ out, const void* __restrict__ xsrc) {
    int flag = block_flag((const unsigned int*)xsrc);
    int lane = threadIdx.x & 63;
    int node = blockIdx.x * 4 + (threadIdx.x >> 6);
    if (node >= N) return;
    float h[2];
    agg_core<2>(Hin, offsets, edges, dis, node, lane, N, Etot, b3, 1, h);

    int fo = lane * 2;
    float p[16];
#pragma unroll
    for (int j = 0; j < 16; ++j)
        p[j] = h[0] * Wp[fo * 16 + j] + h[1] * Wp[(fo + 1) * 16 + j];
#pragma unroll
    for (int m = 1; m < 64; m <<= 1) {
#pragma unroll
        for (int j = 0; j < 16; ++j) p[j] += __shfl_xor(p[j], m, 64);
    }
    float a0 = 0.f, a1 = 0.f;
    if (lane < 32) {
        float s = bf1v[lane];
#pragma unroll
        for (int k = 0; k < 16; ++k) s += (p[k] + bp[k]) * Wf1[k * 32 + lane];
        s = (s > 0.f) ? s : s * NEG_SLOPE;
        a0 = s * Wf2[lane * 2 + 0];
        a1 = s * Wf2[lane * 2 + 1];
    }
#pragma unroll
    for (int m = 1; m < 64; m <<= 1) {
        a0 += __shfl_xor(a0, m, 64);
        a1 += __shfl_xor(a1, m, 64);
    }
    if (lane == 0) {
        float o0 = a0 + bf2v[0];
        float o1 = a1 + bf2v[1];
        if (flag) {
            unsigned int w = ((unsigned int)f2us(o1) << 16) | f2us(o0);
            *(unsigned int*)((ushort_t*)out + (size_t)node * 2) = w;
        } else {
            *(float2*)((float*)out + (size_t)node * 2) = make_float2(o0, o1);
        }
    }
}

// ---------------------------------------------------------------- MFMA GEMM
// 128x64 tile: 4 waves (2x2), wave = 64x32 (4x2 tiles of 16x16x32), fp32 acc.
__global__ __launch_bounds__(256) void mfma_gemm_kernel(
    const ushort_t* __restrict__ A, const ushort_t* __restrict__ Bt,
    ushort_t* __restrict__ C,
    int M, int K, int Nn, const float* __restrict__ bias, int do_lrelu) {
    __shared__ ushort_t As[128 * 40];
    __shared__ ushort_t Bs[64 * 40];

    int tid = threadIdx.x;
    int row0 = blockIdx.y * 128;
    int col0 = blockIdx.x * 64;
    int lane = tid & 63;
    int w = tid >> 6;
    int quad = lane >> 4;
    int col = lane & 15;
    int wr = (w >> 1) * 64;
    int wc = (w & 1) * 32;

    floatx4 acc[4][2];
#pragma unroll
    for (int i = 0; i < 4; ++i)
#pragma unroll
        for (int j = 0; j < 2; ++j) acc[i][j] = (floatx4){0.f, 0.f, 0.f, 0.f};

    int arow = tid >> 1;
    int aseg = (tid & 1) * 16;
    int bcol = tid >> 2;
    int bseg = (tid & 3) * 8;

    for (int k0 = 0; k0 < K; k0 += 32) {
        {
            uint4 h0 = {0, 0, 0, 0}, h1 = {0, 0, 0, 0};
            if (row0 + arow < M) {
                size_t g = (size_t)(row0 + arow) * K + k0 + aseg;
                h0 = *(const uint4*)(A + g);
                h1 = *(const uint4*)(A + g + 8);
            }
            int lb = arow * 40 + aseg;
            *(uint4*)&As[lb] = h0;
            *(uint4*)&As[lb + 8] = h1;
        }
        {
            size_t g = (size_t)(col0 + bcol) * K + k0 + bseg;
            *(uint4*)&Bs[bcol * 40 + bseg] = *(const uint4*)(Bt + g);
        }
        __syncthreads();

        short8v af[4], bf[2];
#pragma unroll
        for (int rt = 0; rt < 4; ++rt)
            af[rt] = *(const short8v*)&As[(wr + rt * 16 + col) * 40 + quad * 8];
#pragma unroll
        for (int ct = 0; ct < 2; ++ct)
            bf[ct] = *(const short8v*)&Bs[(wc + ct * 16 + col) * 40 + quad * 8];
#pragma unroll
        for (int rt = 0; rt < 4; ++rt)
#pragma unroll
            for (int ct = 0; ct < 2; ++ct)
                acc[rt][ct] = __builtin_amdgcn_mfma_f32_16x16x32_bf16(
                    af[rt], bf[ct], acc[rt][ct], 0, 0, 0);
        __syncthreads();
    }

#pragma unroll
    for (int rt = 0; rt < 4; ++rt) {
#pragma unroll
        for (int ct = 0; ct < 2; ++ct) {
            int gcol = col0 + wc + ct * 16 + col;
            float bv = bias ? bias[gcol] : 0.f;
#pragma unroll
            for (int r = 0; r < 4; ++r) {
                int grow = row0 + wr + rt * 16 + quad * 4 + r;
                if (grow >= M) continue;
                float v = acc[rt][ct][r] + bv;
                if (do_lrelu) v = (v > 0.f) ? v : v * NEG_SLOPE;
                C[(size_t)grow * Nn + gcol] = f2us(v);
            }
        }
    }
}

// ---------------------------------------------------------------- launch
extern "C" void kernel_launch(void* const* d_in, const int* in_sizes, int n_in,
                              void* d_out, int out_size, void* d_ws, size_t ws_size,
                              hipStream_t stream) {
    const int* ei = (const int*)d_in[1];

    const int N = in_sizes[0] / 128;   // 20000
    const int E = in_sizes[1] / 2;     // 320000
    const int Etot = E + N;
    const int nb = (N + 1023) / 1024;  // 20
    const int* srcv = ei;
    const int* dstv = ei + E;

    uintptr_t p = (uintptr_t)d_ws;
    auto alloc = [&](size_t bytes) -> void* {
        p = (p + 255) & ~(uintptr_t)255;
        void* r = (void*)p;
        p += bytes;
        return r;
    };
    // deg + bar contiguous: zeroed together by prep task
    int*      deg     = (int*)alloc((size_t)(N + 4) * 4);
    int*      bar     = deg + N;
    int*      offsets = (int*)alloc((size_t)(N + 1) * 4);
    int*      cursor  = (int*)alloc((size_t)N * 4);
    float*    dis     = (float*)alloc((size_t)N * 4);
    int*      bsum    = (int*)alloc((size_t)(nb + 1) * 4);
    int2*     edges   = (int2*)alloc((size_t)Etot * 8);
    ushort_t* xb      = (ushort_t*)alloc((size_t)N * 128 * 2);

    const int K1 = 128, N1 = 512, K2 = 512, N2 = 256, K3 = 256, N3 = 128;
    ushort_t* W1t = (ushort_t*)alloc((size_t)K1 * N1 * 2);
    ushort_t* W2t = (ushort_t*)alloc((size_t)K2 * N2 * 2);
    ushort_t* W3t = (ushort_t*)alloc((size_t)K3 * N3 * 2);

    // small fp32 tensors: b1,b2,b3, Wp,bp, Wf1,bf1, Wf2,bf2
    float* smalls[9];
    const int wmap[9] = {4, 6, 8, 9, 10, 11, 12, 13, 14};
    for (int t = 0; t < 9; ++t)
        smalls[t] = (float*)alloc((size_t)in_sizes[wmap[t]] * 4);
    const float *b1 = smalls[0], *b2 = smalls[1], *b3 = smalls[2];
    const float *Wp = smalls[3], *bp = smalls[4];
    const float *Wf1 = smalls[5], *bf1v = smalls[6];
    const float *Wf2 = smalls[7], *bf2v = smalls[8];

    // big buffers (aliased by lifetime)
    ushort_t* BufT0 = (ushort_t*)alloc((size_t)N * 128 * 2);   // t0, then t3
    ushort_t* BufH1 = (ushort_t*)alloc((size_t)N * 512 * 2);   // H1, then H2
    ushort_t* BufT2 = (ushort_t*)alloc((size_t)N * 256 * 2);   // t2
    ushort_t* t0 = BufT0;
    ushort_t* t3 = BufT0;
    ushort_t* H1 = BufH1;
    ushort_t* H2 = BufH1;
    ushort_t* t2 = BufT2;

    // ---- prep: 9 converts, 3 transposes, zero deg+bar, convert x ----
    {
        PrepDesc pd;
        for (int t = 0; t < 9; ++t) {
            pd.src[t] = d_in[wmap[t]];
            pd.dst[t] = smalls[t];
            pd.n[t] = in_sizes[wmap[t]];
            pd.K[t] = 0; pd.Nn[t] = 0;
        }
        pd.src[9]  = d_in[3]; pd.dst[9]  = W1t; pd.n[9]  = K1 * N1; pd.K[9]  = K1; pd.Nn[9]  = N1;
        pd.src[10] = d_in[5]; pd.dst[10] = W2t; pd.n[10] = K2 * N2; pd.K[10] = K2; pd.Nn[10] = N2;
        pd.src[11] = d_in[7]; pd.dst[11] = W3t; pd.n[11] = K3 * N3; pd.K[11] = K3; pd.Nn[11] = N3;
        pd.src[12] = nullptr; pd.dst[12] = deg; pd.n[12] = N + 4; pd.K[12] = -1; pd.Nn[12] = 0;
        pd.src[13] = d_in[0]; pd.dst[13] = xb;  pd.n[13] = N * 128; pd.K[13] = -2; pd.Nn[13] = 0;
        dim3 g((K2 * N2 + 255) / 256, 14);
        prep_small_kernel<<<g, 256, 0, stream>>>(pd, d_in[0]);
    }

    // ---- CSR build: one mega kernel ----
    csr_mega_kernel<<<nb, 1024, 0, stream>>>(srcv, dstv, deg, bar, offsets, cursor,
                                             dis, bsum, edges, E, N, Etot, nb);

    int aggGrid = (N + 3) / 4;
    // t0 = A x -> bf16 [N,128]
    agg_kernel<2><<<aggGrid, 256, 0, stream>>>(xb, t0, offsets, edges, dis,
                                               N, Etot, nullptr, 0);
    // H1 = lrelu(t0 W1 + b1) -> bf16 [N,512]
    {
        dim3 g(N1 / 64, (N + 127) / 128);
        mfma_gemm_kernel<<<g, 256, 0, stream>>>(t0, W1t, H1, N, K1, N1, b1, 1);
    }
    // t2 = H1 W2 -> bf16 [N,256]
    {
        dim3 g(N2 / 64, (N + 127) / 128);
        mfma_gemm_kernel<<<g, 256, 0, stream>>>(H1, W2t, t2, N, K2, N2, nullptr, 0);
    }
    // H2 = lrelu(A t2 + b2) -> bf16 [N,256]
    agg_kernel<4><<<aggGrid, 256, 0, stream>>>(t2, H2, offsets, edges, dis,
                                               N, Etot, b2, 1);
    // t3 = H2 W3 -> bf16 [N,128]
    {
        dim3 g(N3 / 64, (N + 127) / 128);
        mfma_gemm_kernel<<<g, 256, 0, stream>>>(H2, W3t, t3, N, K3, N3, nullptr, 0);
    }
    // H3 = lrelu(A t3 + b3) fused with head -> out
    agg_head_kernel<<<aggGrid, 256, 0, stream>>>(t3, offsets, edges, dis, N, Etot,
                                                 b3, Wp, bp, Wf1, bf1v, Wf2, bf2v,
                                                 d_out, d_in[0]);
}

// Round 12
// 270.309 us; speedup vs baseline: 1.2324x; 1.2324x over previous
//
#include <hip/hip_runtime.h>
#include <hip/hip_bf16.h>

typedef __hip_bfloat16 bf16;
typedef unsigned short ushort_t;
typedef __attribute__((ext_vector_type(8))) short short8v;
typedef __attribute__((ext_vector_type(4))) float floatx4;

#define NEG_SLOPE 0.15f

__device__ __forceinline__ float us2f(unsigned short u) {
    unsigned int x = ((unsigned int)u) << 16;
    float f;
    __builtin_memcpy(&f, &x, 4);
    return f;
}
__device__ __forceinline__ unsigned short f2us(float v) {
    bf16 h = __float2bfloat16(v);
    unsigned short u;
    __builtin_memcpy(&u, &h, 2);
    return u;
}

// ---------------------------------------------------------- per-block dtype flag
// flag=1 if x is packed bf16, 0 if fp32. Votes on first 256 words of x.
// Requires blockDim.x >= 256; call before any early return.
__device__ __forceinline__ int block_flag(const unsigned int* __restrict__ xw) {
    __shared__ int cnt;
    if (threadIdx.x == 0) cnt = 0;
    __syncthreads();
    if (threadIdx.x < 256) {
        unsigned int w = xw[threadIdx.x];
        unsigned int e = (w >> 7) & 0xFF;
        if ((w & 0xFFFF) == 0 || (e >= 100 && e <= 140)) atomicAdd(&cnt, 1);
    }
    __syncthreads();
    return cnt >= 150;
}

// ---------------------------------------------------------------- prep kernel
// task types: K==0 -> fp32 convert; K>0 -> transpose W[K x Nn] -> bf16 Wt[Nn x K];
// K==-1 -> zero ints; K==-2 -> convert x to bf16 (grid-stride).
struct PrepDesc {
    const void* src[14];
    void* dst[14];
    int n[14];
    int K[14], Nn[14];
};

__global__ void prep_small_kernel(PrepDesc d, const void* __restrict__ xsrc) {
    int f = block_flag((const unsigned int*)xsrc);
    int t = blockIdx.y;
    int Kt = d.K[t];
    int nt = d.n[t];
    if (Kt == -2) {
        ushort_t* out = (ushort_t*)d.dst[t];
        const void* in = d.src[t];
        int stride = gridDim.x * blockDim.x;
        for (int i = blockIdx.x * blockDim.x + threadIdx.x; i < nt; i += stride)
            out[i] = f ? ((const unsigned short*)in)[i] : f2us(((const float*)in)[i]);
        return;
    }
    int i = blockIdx.x * blockDim.x + threadIdx.x;
    if (i >= nt) return;
    if (Kt == -1) {
        ((int*)d.dst[t])[i] = 0;
    } else if (Kt == 0) {
        ((float*)d.dst[t])[i] = f ? us2f(((const unsigned short*)d.src[t])[i])
                                  : ((const float*)d.src[t])[i];
    } else {
        int K = Kt, Nn = d.Nn[t];
        int n = i / K, k = i - n * K;
        size_t si = (size_t)k * Nn + n;
        ((ushort_t*)d.dst[t])[i] = f ? ((const unsigned short*)d.src[t])[si]
                                     : f2us(((const float*)d.src[t])[si]);
    }
}

// ---------------------------------------------------------------- CSR build
__global__ void count_deg_kernel(const int* __restrict__ dst, int* __restrict__ deg,
                                 int E, int N) {
    int i = blockIdx.x * blockDim.x + threadIdx.x;
    if (i < E) {
        int d = dst[i];
        d = d < 0 ? 0 : (d >= N ? N - 1 : d);
        atomicAdd(&deg[d], 1);
    }
}

// single-dispatch scan with decoupled lookback: block b publishes its total
// (value+1, nonzero == ready) then sums predecessors. bsumf zeroed by prep.
__global__ void scan_merged_kernel(const int* __restrict__ deg, int* __restrict__ offsets,
                                   int* __restrict__ cursor, float* __restrict__ dis,
                                   int* __restrict__ bsumf, int N) {
    __shared__ int sh[1024];
    __shared__ int base_s;
    int tid = threadIdx.x;
    int b = blockIdx.x;
    int i = b * 1024 + tid;
    int v = (i < N) ? (deg[i] + 1) : 0;
    sh[tid] = v;
    __syncthreads();
    for (int off = 1; off < 1024; off <<= 1) {
        int t = (tid >= off) ? sh[tid - off] : 0;
        __syncthreads();
        sh[tid] += t;
        __syncthreads();
    }
    if (tid == 0) {
        __hip_atomic_store(&bsumf[b], sh[1023] + 1, __ATOMIC_RELEASE,
                           __HIP_MEMORY_SCOPE_AGENT);
        int a = 0;
        for (int pb = 0; pb < b; ++pb) {
            int val;
            do {
                val = __hip_atomic_load(&bsumf[pb], __ATOMIC_ACQUIRE,
                                        __HIP_MEMORY_SCOPE_AGENT);
            } while (val == 0);
            a += val - 1;
        }
        base_s = a;
    }
    __syncthreads();
    if (i < N) {
        int base = base_s;
        int d = deg[i] + 1;
        int inc = sh[tid];
        int excl = base + inc - d;
        offsets[i] = excl;
        cursor[i] = excl;
        dis[i] = rsqrtf((float)d);
        if (i == N - 1) offsets[N] = base + inc;
    }
}

// edges[pos] = {src, bits(dis[src])}
__global__ void fill_csr_kernel(const int* __restrict__ src, const int* __restrict__ dst,
                                const float* __restrict__ dis, int* __restrict__ cursor,
                                int2* __restrict__ edges, int E, int N, int Etot) {
    int i = blockIdx.x * blockDim.x + threadIdx.x;
    int s, d;
    if (i < E) { s = src[i]; d = dst[i]; }
    else if (i < Etot) { s = d = i - E; }
    else return;
    s = s < 0 ? 0 : (s >= N ? N - 1 : s);
    d = d < 0 ? 0 : (d >= N ? N - 1 : d);
    int pos = atomicAdd(&cursor[d], 1);
    if (pos >= 0 && pos < Etot) edges[pos] = make_int2(s, __float_as_int(dis[s]));
}

// ---------------------------------------------------------------- aggregation
template <int VEC> struct LdT;
template <> struct LdT<2> { typedef unsigned int T; };
template <> struct LdT<4> { typedef uint2 T; };

template <int VEC>
__device__ __forceinline__ void addv(typename LdT<VEC>::T u, float w, float* acc);
template <>
__device__ __forceinline__ void addv<2>(unsigned int u, float w, float* acc) {
    acc[0] += w * us2f((unsigned short)(u & 0xFFFF));
    acc[1] += w * us2f((unsigned short)(u >> 16));
}
template <>
__device__ __forceinline__ void addv<4>(uint2 u, float w, float* acc) {
    acc[0] += w * us2f((unsigned short)(u.x & 0xFFFF));
    acc[1] += w * us2f((unsigned short)(u.x >> 16));
    acc[2] += w * us2f((unsigned short)(u.y & 0xFFFF));
    acc[3] += w * us2f((unsigned short)(u.y >> 16));
}

// core gather+accumulate for one node; returns post-bias, post-lrelu values in outv
template <int VEC>
__device__ __forceinline__ void agg_core(
    const ushort_t* __restrict__ Hin, const int* __restrict__ offsets,
    const int2* __restrict__ edges, const float* __restrict__ dis,
    int node, int lane, int N, int Etot,
    const float* __restrict__ bias, int do_lrelu, float* outv) {
    typedef typename LdT<VEC>::T LT;
    const int F = VEC * 64;
    int beg = offsets[node], end = offsets[node + 1];
    beg = beg < 0 ? 0 : (beg > Etot ? Etot : beg);
    end = end < beg ? beg : (end > Etot ? Etot : end);

    float acc[VEC];
#pragma unroll
    for (int v = 0; v < VEC; ++v) acc[v] = 0.f;

    int fo = lane * VEC;
    int e = beg;
    for (; e + 8 <= end; e += 8) {
        int2 r[8];
#pragma unroll
        for (int j = 0; j < 8; ++j) r[j] = edges[e + j];
        LT u[8];
#pragma unroll
        for (int j = 0; j < 8; ++j) {
            int s = r[j].x;
            s = s < 0 ? 0 : (s >= N ? N - 1 : s);
            u[j] = *(const LT*)(Hin + (size_t)s * F + fo);
        }
#pragma unroll
        for (int j = 0; j < 8; ++j) addv<VEC>(u[j], __int_as_float(r[j].y), acc);
    }
    if (e + 4 <= end) {
        int2 r[4];
#pragma unroll
        for (int j = 0; j < 4; ++j) r[j] = edges[e + j];
        LT u[4];
#pragma unroll
        for (int j = 0; j < 4; ++j) {
            int s = r[j].x;
            s = s < 0 ? 0 : (s >= N ? N - 1 : s);
            u[j] = *(const LT*)(Hin + (size_t)s * F + fo);
        }
#pragma unroll
        for (int j = 0; j < 4; ++j) addv<VEC>(u[j], __int_as_float(r[j].y), acc);
        e += 4;
    }
    for (; e < end; ++e) {
        int2 r = edges[e];
        int s = r.x;
        s = s < 0 ? 0 : (s >= N ? N - 1 : s);
        LT u = *(const LT*)(Hin + (size_t)s * F + fo);
        addv<VEC>(u, __int_as_float(r.y), acc);
    }

    float dn = dis[node];
#pragma unroll
    for (int v = 0; v < VEC; ++v) {
        float a = acc[v] * dn;
        if (bias) a += bias[fo + v];
        if (do_lrelu) a = (a > 0.f) ? a : a * NEG_SLOPE;
        outv[v] = a;
    }
}

// standalone agg: bf16 packed output
template <int VEC>
__global__ __launch_bounds__(256) void agg_kernel(
    const ushort_t* __restrict__ Hin, ushort_t* __restrict__ OutB,
    const int* __restrict__ offsets, const int2* __restrict__ edges,
    const float* __restrict__ dis, int N, int Etot,
    const float* __restrict__ bias, int do_lrelu) {
    int lane = threadIdx.x & 63;
    int node = blockIdx.x * 4 + (threadIdx.x >> 6);
    if (node >= N) return;
    float outv[VEC];
    agg_core<VEC>(Hin, offsets, edges, dis, node, lane, N, Etot, bias, do_lrelu, outv);
    size_t base = (size_t)node * (VEC * 64) + lane * VEC;
    if (VEC == 2) {
        unsigned int w = ((unsigned int)f2us(outv[1]) << 16) | f2us(outv[0]);
        *(unsigned int*)(OutB + base) = w;
    } else {
        uint2 w;
        w.x = ((unsigned int)f2us(outv[1]) << 16) | f2us(outv[0]);
        w.y = ((unsigned int)f2us(outv[3]) << 16) | f2us(outv[2]);
        *(uint2*)(OutB + base) = w;
    }
}

// fused agg (VEC=2, F=128) + head MLP: H3 stays in fp32 registers, then
// 128->16 via wave butterfly, 16->32->2 lane-parallel, lane 0 stores.
__global__ __launch_bounds__(256) void agg_head_kernel(
    const ushort_t* __restrict__ Hin,
    const int* __restrict__ offsets, const int2* __restrict__ edges,
    const float* __restrict__ dis, int N, int Etot,
    const float* __restrict__ b3,
    const float* __restrict__ Wp, const float* __restrict__ bp,
    const float* __restrict__ Wf1, const float* __restrict__ bf1v,
    const float* __restrict__ Wf2, const float* __restrict__ bf2v,
    void* __restrict__ out, const void* __restrict__ xsrc) {
    int flag = block_flag((const unsigned int*)xsrc);
    int lane = threadIdx.x & 63;
    int node = blockIdx.x * 4 + (threadIdx.x >> 6);
    if (node >= N) return;
    float h[2];
    agg_core<2>(Hin, offsets, edges, dis, node, lane, N, Etot, b3, 1, h);

    int fo = lane * 2;
    float p[16];
#pragma unroll
    for (int j = 0; j < 16; ++j)
        p[j] = h[0] * Wp[fo * 16 + j] + h[1] * Wp[(fo + 1) * 16 + j];
#pragma unroll
    for (int m = 1; m < 64; m <<= 1) {
#pragma unroll
        for (int j = 0; j < 16; ++j) p[j] += __shfl_xor(p[j], m, 64);
    }
    float a0 = 0.f, a1 = 0.f;
    if (lane < 32) {
        float s = bf1v[lane];
#pragma unroll
        for (int k = 0; k < 16; ++k) s += (p[k] + bp[k]) * Wf1[k * 32 + lane];
        s = (s > 0.f) ? s : s * NEG_SLOPE;
        a0 = s * Wf2[lane * 2 + 0];
        a1 = s * Wf2[lane * 2 + 1];
    }
#pragma unroll
    for (int m = 1; m < 64; m <<= 1) {
        a0 += __shfl_xor(a0, m, 64);
        a1 += __shfl_xor(a1, m, 64);
    }
    if (lane == 0) {
        float o0 = a0 + bf2v[0];
        float o1 = a1 + bf2v[1];
        if (flag) {
            unsigned int w = ((unsigned int)f2us(o1) << 16) | f2us(o0);
            *(unsigned int*)((ushort_t*)out + (size_t)node * 2) = w;
        } else {
            *(float2*)((float*)out + (size_t)node * 2) = make_float2(o0, o1);
        }
    }
}

// ---------------------------------------------------------------- MFMA GEMM
// 128x64 tile: 4 waves (2x2), wave = 64x32 (4x2 tiles of 16x16x32), fp32 acc.
__global__ __launch_bounds__(256) void mfma_gemm_kernel(
    const ushort_t* __restrict__ A, const ushort_t* __restrict__ Bt,
    ushort_t* __restrict__ C,
    int M, int K, int Nn, const float* __restrict__ bias, int do_lrelu) {
    __shared__ ushort_t As[128 * 40];
    __shared__ ushort_t Bs[64 * 40];

    int tid = threadIdx.x;
    int row0 = blockIdx.y * 128;
    int col0 = blockIdx.x * 64;
    int lane = tid & 63;
    int w = tid >> 6;
    int quad = lane >> 4;
    int col = lane & 15;
    int wr = (w >> 1) * 64;
    int wc = (w & 1) * 32;

    floatx4 acc[4][2];
#pragma unroll
    for (int i = 0; i < 4; ++i)
#pragma unroll
        for (int j = 0; j < 2; ++j) acc[i][j] = (floatx4){0.f, 0.f, 0.f, 0.f};

    int arow = tid >> 1;
    int aseg = (tid & 1) * 16;
    int bcol = tid >> 2;
    int bseg = (tid & 3) * 8;

    for (int k0 = 0; k0 < K; k0 += 32) {
        {
            uint4 h0 = {0, 0, 0, 0}, h1 = {0, 0, 0, 0};
            if (row0 + arow < M) {
                size_t g = (size_t)(row0 + arow) * K + k0 + aseg;
                h0 = *(const uint4*)(A + g);
                h1 = *(const uint4*)(A + g + 8);
            }
            int lb = arow * 40 + aseg;
            *(uint4*)&As[lb] = h0;
            *(uint4*)&As[lb + 8] = h1;
        }
        {
            size_t g = (size_t)(col0 + bcol) * K + k0 + bseg;
            *(uint4*)&Bs[bcol * 40 + bseg] = *(const uint4*)(Bt + g);
        }
        __syncthreads();

        short8v af[4], bf[2];
#pragma unroll
        for (int rt = 0; rt < 4; ++rt)
            af[rt] = *(const short8v*)&As[(wr + rt * 16 + col) * 40 + quad * 8];
#pragma unroll
        for (int ct = 0; ct < 2; ++ct)
            bf[ct] = *(const short8v*)&Bs[(wc + ct * 16 + col) * 40 + quad * 8];
#pragma unroll
        for (int rt = 0; rt < 4; ++rt)
#pragma unroll
            for (int ct = 0; ct < 2; ++ct)
                acc[rt][ct] = __builtin_amdgcn_mfma_f32_16x16x32_bf16(
                    af[rt], bf[ct], acc[rt][ct], 0, 0, 0);
        __syncthreads();
    }

#pragma unroll
    for (int rt = 0; rt < 4; ++rt) {
#pragma unroll
        for (int ct = 0; ct < 2; ++ct) {
            int gcol = col0 + wc + ct * 16 + col;
            float bv = bias ? bias[gcol] : 0.f;
#pragma unroll
            for (int r = 0; r < 4; ++r) {
                int grow = row0 + wr + rt * 16 + quad * 4 + r;
                if (grow >= M) continue;
                float v = acc[rt][ct][r] + bv;
                if (do_lrelu) v = (v > 0.f) ? v : v * NEG_SLOPE;
                C[(size_t)grow * Nn + gcol] = f2us(v);
            }
        }
    }
}

// ---------------------------------------------------------------- launch
extern "C" void kernel_launch(void* const* d_in, const int* in_sizes, int n_in,
                              void* d_out, int out_size, void* d_ws, size_t ws_size,
                              hipStream_t stream) {
    const int* ei = (const int*)d_in[1];

    const int N = in_sizes[0] / 128;   // 20000
    const int E = in_sizes[1] / 2;     // 320000
    const int Etot = E + N;
    const int nb = (N + 1023) / 1024;  // 20
    const int* srcv = ei;
    const int* dstv = ei + E;

    uintptr_t p = (uintptr_t)d_ws;
    auto alloc = [&](size_t bytes) -> void* {
        p = (p + 255) & ~(uintptr_t)255;
        void* r = (void*)p;
        p += bytes;
        return r;
    };
    // deg + bsumf contiguous: zeroed together by prep task 12
    int*      deg     = (int*)alloc((size_t)(N + nb + 1) * 4);
    int*      bsumf   = deg + N;
    int*      offsets = (int*)alloc((size_t)(N + 1) * 4);
    int*      cursor  = (int*)alloc((size_t)N * 4);
    float*    dis     = (float*)alloc((size_t)N * 4);
    int2*     edges   = (int2*)alloc((size_t)Etot * 8);
    ushort_t* xb      = (ushort_t*)alloc((size_t)N * 128 * 2);

    const int K1 = 128, N1 = 512, K2 = 512, N2 = 256, K3 = 256, N3 = 128;
    ushort_t* W1t = (ushort_t*)alloc((size_t)K1 * N1 * 2);
    ushort_t* W2t = (ushort_t*)alloc((size_t)K2 * N2 * 2);
    ushort_t* W3t = (ushort_t*)alloc((size_t)K3 * N3 * 2);

    // small fp32 tensors: b1,b2,b3, Wp,bp, Wf1,bf1, Wf2,bf2
    float* smalls[9];
    const int wmap[9] = {4, 6, 8, 9, 10, 11, 12, 13, 14};
    for (int t = 0; t < 9; ++t)
        smalls[t] = (float*)alloc((size_t)in_sizes[wmap[t]] * 4);
    const float *b1 = smalls[0], *b2 = smalls[1], *b3 = smalls[2];
    const float *Wp = smalls[3], *bp = smalls[4];
    const float *Wf1 = smalls[5], *bf1v = smalls[6];
    const float *Wf2 = smalls[7], *bf2v = smalls[8];

    // big buffers (aliased by lifetime)
    ushort_t* BufT0 = (ushort_t*)alloc((size_t)N * 128 * 2);   // t0, then t3
    ushort_t* BufH1 = (ushort_t*)alloc((size_t)N * 512 * 2);   // H1, then H2
    ushort_t* BufT2 = (ushort_t*)alloc((size_t)N * 256 * 2);   // t2
    ushort_t* t0 = BufT0;
    ushort_t* t3 = BufT0;
    ushort_t* H1 = BufH1;
    ushort_t* H2 = BufH1;
    ushort_t* t2 = BufT2;

    // ---- prep: 9 converts, 3 transposes, zero deg+bsumf, convert x ----
    {
        PrepDesc pd;
        for (int t = 0; t < 9; ++t) {
            pd.src[t] = d_in[wmap[t]];
            pd.dst[t] = smalls[t];
            pd.n[t] = in_sizes[wmap[t]];
            pd.K[t] = 0; pd.Nn[t] = 0;
        }
        pd.src[9]  = d_in[3]; pd.dst[9]  = W1t; pd.n[9]  = K1 * N1; pd.K[9]  = K1; pd.Nn[9]  = N1;
        pd.src[10] = d_in[5]; pd.dst[10] = W2t; pd.n[10] = K2 * N2; pd.K[10] = K2; pd.Nn[10] = N2;
        pd.src[11] = d_in[7]; pd.dst[11] = W3t; pd.n[11] = K3 * N3; pd.K[11] = K3; pd.Nn[11] = N3;
        pd.src[12] = nullptr; pd.dst[12] = deg; pd.n[12] = N + nb + 1; pd.K[12] = -1; pd.Nn[12] = 0;
        pd.src[13] = d_in[0]; pd.dst[13] = xb;  pd.n[13] = N * 128;    pd.K[13] = -2; pd.Nn[13] = 0;
        dim3 g((K2 * N2 + 255) / 256, 14);
        prep_small_kernel<<<g, 256, 0, stream>>>(pd, d_in[0]);
    }

    // ---- CSR build: wide count -> lookback scan -> wide fill ----
    count_deg_kernel<<<(E + 255) / 256, 256, 0, stream>>>(dstv, deg, E, N);
    scan_merged_kernel<<<nb, 1024, 0, stream>>>(deg, offsets, cursor, dis, bsumf, N);
    fill_csr_kernel<<<(Etot + 255) / 256, 256, 0, stream>>>(srcv, dstv, dis, cursor,
                                                            edges, E, N, Etot);

    int aggGrid = (N + 3) / 4;
    // t0 = A x -> bf16 [N,128]
    agg_kernel<2><<<aggGrid, 256, 0, stream>>>(xb, t0, offsets, edges, dis,
                                               N, Etot, nullptr, 0);
    // H1 = lrelu(t0 W1 + b1) -> bf16 [N,512]
    {
        dim3 g(N1 / 64, (N + 127) / 128);
        mfma_gemm_kernel<<<g, 256, 0, stream>>>(t0, W1t, H1, N, K1, N1, b1, 1);
    }
    // t2 = H1 W2 -> bf16 [N,256]
    {
        dim3 g(N2 / 64, (N + 127) / 128);
        mfma_gemm_kernel<<<g, 256, 0, stream>>>(H1, W2t, t2, N, K2, N2, nullptr, 0);
    }
    // H2 = lrelu(A t2 + b2) -> bf16 [N,256]
    agg_kernel<4><<<aggGrid, 256, 0, stream>>>(t2, H2, offsets, edges, dis,
                                               N, Etot, b2, 1);
    // t3 = H2 W3 -> bf16 [N,128]
    {
        dim3 g(N3 / 64, (N + 127) / 128);
        mfma_gemm_kernel<<<g, 256, 0, stream>>>(H2, W3t, t3, N, K3, N3, nullptr, 0);
    }
    // H3 = lrelu(A t3 + b3) fused with head -> out
    agg_head_kernel<<<aggGrid, 256, 0, stream>>>(t3, offsets, edges, dis, N, Etot,
                                                 b3, Wp, bp, Wf1, bf1v, Wf2, bf2v,
                                                 d_out, d_in[0]);
}